// Round 21
// baseline (137.608 us; speedup 1.0000x reference)
//
#include <hip/hip_runtime.h>
#include <hip/hip_bf16.h>
#include <stdint.h>

// ---------------------------------------------------------------------------
// y = w4( s1 ),  s1 = (1-g1)*h1 + z1   (s0 == 1 exactly: tanh saturation)
// R18 verified: h->g->z reorder killed spill (VGPR 120, WRITE 33MB),
//   gates_h512 = 96.2us, total 137.0us.
// Cost model: 1 block/CU, ~4100cy/step vs ~400cy compute -> vmcnt-wait bound
//   with only 6 loads/wave (1 step) in flight at 2 waves/SIMD.
// R21: 3-buffer 2-deep prefetch in gates_h512 (LDS 144KB, vmcnt(12) steady,
//   vmcnt(6)/(0) tail) -> 2 steps of staging slack per wave. Single variable.
// ---------------------------------------------------------------------------

typedef unsigned short u16;
using f32x4  = __attribute__((ext_vector_type(4))) float;
using bf16x8 = __attribute__((ext_vector_type(8))) short;

#define BATCH 16384
#define NIN   256
#define NHID  1024
#define NOUT  256

#define BM 128
#define BN 128
#define BK2 64   // K-chunk per pipeline step (128B rows in LDS)

__device__ __forceinline__ u16 f2bf(float f) {
  unsigned u = __builtin_bit_cast(unsigned, f);
  unsigned r = 0x7fffu + ((u >> 16) & 1u);
  return (u16)((u + r) >> 16);
}
__device__ __forceinline__ float bf2f(u16 h) {
  unsigned u = ((unsigned)h) << 16;
  return __builtin_bit_cast(float, u);
}
__device__ __forceinline__ float fast_tanh(float x) {
  float cx = fminf(fmaxf(x, -15.f), 15.f);
  float e  = __expf(2.f * cx);
  return (e - 1.f) / (e + 1.f);
}

__device__ __forceinline__ void gload_lds16(const u16* g, u16* l) {
  __builtin_amdgcn_global_load_lds(
      (__attribute__((address_space(1))) void*)(const_cast<u16*>(g)),
      (__attribute__((address_space(3))) void*)(l),
      16, 0, 0);
}

// ================= 128^2 / 4-wave machinery (R8/R14, verified) ==============

__device__ __forceinline__ void stage64(const u16* g0, int ld, u16* lds) {
  int t = threadIdx.x;
#pragma unroll
  for (int iss = 0; iss < 4; ++iss) {
    int idx = t + iss * 256;
    int row = idx >> 3;
    int j   = idx & 7;
    int c   = (j ^ (row & 7)) << 3;
    gload_lds16(g0 + (size_t)row * ld + c, lds + (size_t)idx * 8);
  }
}

__device__ __forceinline__ void mfma64(const u16* As, const u16* Bs,
                                       int wm, int wn, int lane,
                                       f32x4 acc[4][4]) {
  int r  = lane & 15;
  int q  = lane >> 4;
  int xr = r & 7;
#pragma unroll
  for (int ks = 0; ks < 2; ++ks) {
    int cx = ((ks * 4 + q) ^ xr) << 3;
    bf16x8 a[4], b[4];
#pragma unroll
    for (int i = 0; i < 4; ++i)
      a[i] = *(const bf16x8*)(As + (size_t)((wm + i * 16 + r) * BK2 + cx));
#pragma unroll
    for (int j = 0; j < 4; ++j)
      b[j] = *(const bf16x8*)(Bs + (size_t)((wn + j * 16 + r) * BK2 + cx));
#pragma unroll
    for (int i = 0; i < 4; ++i)
#pragma unroll
      for (int j = 0; j < 4; ++j)
        acc[i][j] = __builtin_amdgcn_mfma_f32_16x16x32_bf16(a[i], b[j], acc[i][j], 0, 0, 0);
  }
}

__device__ __forceinline__ void pipe_step(const u16* At, int lda,
                                          const u16* Bt, int ldb,
                                          int t, int STEPS,
                                          u16* Ac, u16* Bc, u16* An, u16* Bn,
                                          int wm, int wn, int lane,
                                          f32x4 acc[4][4]) {
  if (t + 1 < STEPS) {
    stage64(At + (size_t)(t + 1) * BK2, lda, An);
    stage64(Bt + (size_t)(t + 1) * BK2, ldb, Bn);
    asm volatile("s_waitcnt vmcnt(8)" ::: "memory");
  } else {
    asm volatile("s_waitcnt vmcnt(0)" ::: "memory");
  }
  __builtin_amdgcn_s_barrier();
  mfma64(Ac, Bc, wm, wn, lane, acc);
  asm volatile("s_waitcnt lgkmcnt(0)" ::: "memory");
  __builtin_amdgcn_s_barrier();
}

template<int STEPS>
__device__ __forceinline__ void gemm_pipe(const u16* A, int lda,
                                          const u16* B, int ldb,
                                          int m0, int n0, u16* sm,
                                          int wm, int wn, int lane,
                                          f32x4 acc[4][4]) {
  const u16* At = A + (size_t)m0 * lda;
  const u16* Bt = B + (size_t)n0 * ldb;
  u16* As0 = sm;          u16* Bs0 = sm + 8192;
  u16* As1 = sm + 16384;  u16* Bs1 = sm + 24576;
  stage64(At, lda, As0);
  stage64(Bt, ldb, Bs0);
  static_assert(STEPS % 2 == 0, "even steps");
#pragma unroll
  for (int tt = 0; tt < STEPS / 2; ++tt) {
    pipe_step(At, lda, Bt, ldb, 2 * tt,     STEPS, As0, Bs0, As1, Bs1, wm, wn, lane, acc);
    pipe_step(At, lda, Bt, ldb, 2 * tt + 1, STEPS, As1, Bs1, As0, Bs0, wm, wn, lane, acc);
  }
}

__device__ __forceinline__ void zero_acc(f32x4 acc[4][4]) {
  f32x4 z = {0.f, 0.f, 0.f, 0.f};
#pragma unroll
  for (int i = 0; i < 4; ++i)
#pragma unroll
    for (int j = 0; j < 4; ++j) acc[i][j] = z;
}

// ================= 256x128 / 8-wave machinery, 3-buffer (R21) ===============
// Per buffer: A 256x64 (16384 u16) + B 128x64 (8192 u16) = 24576 u16 (48KB).
// 3 buffers = 144KB dynamic LDS. Per wave per step: 4 A-issues + 2 B-issues.

__device__ __forceinline__ void stageA8(const u16* g0, int ld, u16* lds) {
  int t = threadIdx.x;
#pragma unroll
  for (int iss = 0; iss < 4; ++iss) {
    int idx = t + iss * 512;        // 0..2047
    int row = idx >> 3;             // 0..255
    int j   = idx & 7;
    int c   = (j ^ (row & 7)) << 3;
    gload_lds16(g0 + (size_t)row * ld + c, lds + (size_t)idx * 8);
  }
}
__device__ __forceinline__ void stageB8(const u16* g0, int ld, u16* lds) {
  int t = threadIdx.x;
#pragma unroll
  for (int iss = 0; iss < 2; ++iss) {
    int idx = t + iss * 512;        // 0..1023
    int row = idx >> 3;             // 0..127
    int j   = idx & 7;
    int c   = (j ^ (row & 7)) << 3;
    gload_lds16(g0 + (size_t)row * ld + c, lds + (size_t)idx * 8);
  }
}

// 3-buffer rotation, 2-deep prefetch. Steady state: steps t+1,t+2 in flight
// (12 loads/wave) -> vmcnt(12) waits step t; tail vmcnt(6)/vmcnt(0).
template<int STEPS>
__device__ __forceinline__ void gemm_pipe8(const u16* A, int lda,
                                           const u16* B, int ldb,
                                           int m0, int n0, u16* sm,
                                           int wm, int wn, int lane,
                                           f32x4 acc[4][4]) {
  const u16* At = A + (size_t)m0 * lda;
  const u16* Bt = B + (size_t)n0 * ldb;
  stageA8(At, lda, sm);
  stageB8(Bt, ldb, sm + 16384);
  if (STEPS > 1) {
    stageA8(At + BK2, lda, sm + 24576);
    stageB8(Bt + BK2, ldb, sm + 24576 + 16384);
  }
#pragma unroll
  for (int t = 0; t < STEPS; ++t) {
    if (t + 2 < STEPS) {
      u16* buf = sm + (size_t)((t + 2) % 3) * 24576;
      stageA8(At + (size_t)(t + 2) * BK2, lda, buf);
      stageB8(Bt + (size_t)(t + 2) * BK2, ldb, buf + 16384);
      asm volatile("s_waitcnt vmcnt(12)" ::: "memory");
    } else if (t + 1 < STEPS) {
      asm volatile("s_waitcnt vmcnt(6)" ::: "memory");
    } else {
      asm volatile("s_waitcnt vmcnt(0)" ::: "memory");
    }
    __builtin_amdgcn_s_barrier();
    u16* cur = sm + (size_t)(t % 3) * 24576;
    mfma64(cur, cur + 16384, wm, wn, lane, acc);
    asm volatile("s_waitcnt lgkmcnt(0)" ::: "memory");
    __builtin_amdgcn_s_barrier();
  }
}

// --------------------------- fused prep kernel ------------------------------

struct Prep {
  const float* x; u16* xa;
  const float* csrc[6]; u16* cdst[6]; int cblk[6];
  const float* w[3]; const float* bb[3]; float* c[3];
};

__global__ __launch_bounds__(256) void k_prep(Prep P) {
  int b = blockIdx.x;
  if (b < 4096) {
    int i = b * 256 + threadIdx.x;
    float4 v = ((const float4*)P.x)[i];
    ushort4 o;
    o.x = f2bf(fabsf(v.x) + 0.1f);
    o.y = f2bf(fabsf(v.y) + 0.1f);
    o.z = f2bf(fabsf(v.z) + 0.1f);
    o.w = f2bf(fabsf(v.w) + 0.1f);
    ((ushort4*)P.xa)[i] = o;
  } else if (b < 6400) {
    int rb = b - 4096;
    int k = 0;
#pragma unroll
    for (int t = 0; t < 5; ++t)
      if (rb >= P.cblk[k]) { rb -= P.cblk[k]; ++k; }
    int i = rb * 256 + threadIdx.x;
    float4 v = ((const float4*)P.csrc[k])[i];
    ushort4 o;
    o.x = f2bf(v.x); o.y = f2bf(v.y); o.z = f2bf(v.z); o.w = f2bf(v.w);
    ((ushort4*)P.cdst[k])[i] = o;
  } else {
    int rb = b - 6400;
    int g = rb >> 10, n = rb & 1023;
    const float* row = P.w[g] + (size_t)n * NHID;
    float s = 0.f;
    for (int k = threadIdx.x; k < NHID; k += 256) s += row[k];
#pragma unroll
    for (int o = 32; o; o >>= 1) s += __shfl_down(s, o, 64);
    __shared__ float sm[4];
    if ((threadIdx.x & 63) == 0) sm[threadIdx.x >> 6] = s;
    __syncthreads();
    if (threadIdx.x == 0) P.c[g][n] = sm[0] + sm[1] + sm[2] + sm[3] + P.bb[g][n];
  }
}

// --------------------------- GEMM passes -----------------------------------

// r1 = tanh(xa @ ur.T + cr)   (R14, verified)
__global__ __launch_bounds__(256) void k_pass_r(const u16* __restrict__ xa,
                                                const u16* __restrict__ ur,
                                                const float* __restrict__ cr,
                                                u16* __restrict__ r1) {
  __shared__ __align__(16) u16 smem[32768];
  int m0 = blockIdx.y * BM, n0 = blockIdx.x * BN;
  int lane = threadIdx.x & 63, wave = threadIdx.x >> 6;
  int wm = (wave >> 1) * 64, wn = (wave & 1) * 64;
  f32x4 acc[4][4];
  zero_acc(acc);
  gemm_pipe<4>(xa, NIN, ur, NIN, m0, n0, smem, wm, wn, lane, acc);

  int crw = (lane >> 4) * 4, cc = lane & 15;
#pragma unroll
  for (int ni = 0; ni < 4; ++ni) {
    int col = n0 + wn + ni * 16 + cc;
    float bias = cr[col];
#pragma unroll
    for (int mi = 0; mi < 4; ++mi)
#pragma unroll
      for (int r = 0; r < 4; ++r) {
        int row = m0 + wm + mi * 16 + crw + r;
        r1[(size_t)row * NHID + col] = f2bf(fast_tanh(acc[mi][ni][r] + bias));
      }
  }
}

// Fused gates+h at 256x128, 8 waves, h->g->z order (R18), 3-buffer pipe (R21).
__global__ __launch_bounds__(512, 1) void k_gates_h512(
    const u16* __restrict__ xa,
    const u16* __restrict__ ug, const u16* __restrict__ uz,
    const u16* __restrict__ uh,
    const float* __restrict__ cg, const float* __restrict__ cz,
    const float* __restrict__ bh,
    const u16* __restrict__ r1, const u16* __restrict__ wh,
    u16* __restrict__ s1) {
  extern __shared__ __align__(16) u16 smem[];   // 144KB dynamic (3 x 48KB)

  int bid = blockIdx.x;
  int xcd = bid & 7;
  int idx = bid >> 3;
  int mb  = xcd * 8 + (idx >> 3);
  int nb  = idx & 7;
  int m0 = mb * 256, n0 = nb * 128;

  int lane = threadIdx.x & 63, wave = threadIdx.x >> 6;
  int wm = (wave >> 1) * 64;
  int wn = (wave & 1) * 64;
  int crw = (lane >> 4) * 4, cc = lane & 15;

  f32x4 acc[4][4];
  unsigned ph[4][4][2];   // packed h, then packed sp = (1-g)*h

  // ---- h (long phase, 20 steps, minimal live state) ----
  zero_acc(acc);
  gemm_pipe8<4>(xa, NIN, uh, NIN, m0, n0, smem, wm, wn, lane, acc);
  gemm_pipe8<16>(r1, NHID, wh, NHID, m0, n0, smem, wm, wn, lane, acc);
#pragma unroll
  for (int ni = 0; ni < 4; ++ni) {
    float bias = bh[n0 + wn + ni * 16 + cc];
#pragma unroll
    for (int mi = 0; mi < 4; ++mi) {
      float h0 = fast_tanh(acc[mi][ni][0] + bias);
      float h1 = fast_tanh(acc[mi][ni][1] + bias);
      float h2 = fast_tanh(acc[mi][ni][2] + bias);
      float h3 = fast_tanh(acc[mi][ni][3] + bias);
      ph[mi][ni][0] = (unsigned)f2bf(h0) | ((unsigned)f2bf(h1) << 16);
      ph[mi][ni][1] = (unsigned)f2bf(h2) | ((unsigned)f2bf(h3) << 16);
    }
  }

  // ---- gate g: sp = (1 - tanh(g+cg)) * h ----
  zero_acc(acc);
  gemm_pipe8<4>(xa, NIN, ug, NIN, m0, n0, smem, wm, wn, lane, acc);
#pragma unroll
  for (int ni = 0; ni < 4; ++ni) {
    float cv = cg[n0 + wn + ni * 16 + cc];
#pragma unroll
    for (int mi = 0; mi < 4; ++mi) {
      float g0 = 1.f - fast_tanh(acc[mi][ni][0] + cv);
      float g1 = 1.f - fast_tanh(acc[mi][ni][1] + cv);
      float g2 = 1.f - fast_tanh(acc[mi][ni][2] + cv);
      float g3 = 1.f - fast_tanh(acc[mi][ni][3] + cv);
      unsigned w0 = ph[mi][ni][0], w1 = ph[mi][ni][1];
      float s0 = g0 * bf2f((u16)(w0 & 0xffff));
      float s1v = g1 * bf2f((u16)(w0 >> 16));
      float s2 = g2 * bf2f((u16)(w1 & 0xffff));
      float s3 = g3 * bf2f((u16)(w1 >> 16));
      ph[mi][ni][0] = (unsigned)f2bf(s0) | ((unsigned)f2bf(s1v) << 16);
      ph[mi][ni][1] = (unsigned)f2bf(s2) | ((unsigned)f2bf(s3) << 16);
    }
  }

  // ---- gate z: s1 = sp + tanh(z+cz), write ----
  zero_acc(acc);
  gemm_pipe8<4>(xa, NIN, uz, NIN, m0, n0, smem, wm, wn, lane, acc);
#pragma unroll
  for (int ni = 0; ni < 4; ++ni) {
    int col = n0 + wn + ni * 16 + cc;
    float cv = cz[col];
#pragma unroll
    for (int mi = 0; mi < 4; ++mi)
#pragma unroll
      for (int r = 0; r < 4; ++r) {
        int row = m0 + wm + mi * 16 + crw + r;
        float z = fast_tanh(acc[mi][ni][r] + cv);
        unsigned w = ph[mi][ni][r >> 1];
        float sp = bf2f((r & 1) ? (u16)(w >> 16) : (u16)(w & 0xffff));
        s1[(size_t)row * NHID + col] = f2bf(sp + z);
      }
  }
}

// y = s1 @ w4.T (fp32 out)   (R14, verified)
__global__ __launch_bounds__(256) void k_pass_c(const u16* __restrict__ s1,
                                                const u16* __restrict__ w4,
                                                float* __restrict__ y) {
  __shared__ __align__(16) u16 smem[32768];
  int m0 = blockIdx.y * BM, n0 = blockIdx.x * BN;
  int lane = threadIdx.x & 63, wave = threadIdx.x >> 6;
  int wm = (wave >> 1) * 64, wn = (wave & 1) * 64;
  f32x4 acc[4][4];
  zero_acc(acc);
  gemm_pipe<16>(s1, NHID, w4, NHID, m0, n0, smem, wm, wn, lane, acc);

  int crw = (lane >> 4) * 4, cc = lane & 15;
#pragma unroll
  for (int ni = 0; ni < 4; ++ni) {
    int col = n0 + wn + ni * 16 + cc;
#pragma unroll
    for (int mi = 0; mi < 4; ++mi)
#pragma unroll
      for (int r = 0; r < 4; ++r) {
        int row = m0 + wm + mi * 16 + crw + r;
        y[(size_t)row * NOUT + col] = acc[mi][ni][r];
      }
  }
}

// --------------------------- host ------------------------------------------

extern "C" void kernel_launch(void* const* d_in, const int* in_sizes, int n_in,
                              void* d_out, int out_size, void* d_ws, size_t ws_size,
                              hipStream_t stream) {
  (void)in_sizes; (void)n_in; (void)out_size; (void)ws_size;

  const float* x    = (const float*)d_in[0];
  const float* ug1  = (const float*)d_in[3];
  const float* wg1w = (const float*)d_in[4];
  const float* wg1b = (const float*)d_in[5];
  const float* uz1  = (const float*)d_in[6];
  const float* wz1w = (const float*)d_in[7];
  const float* wz1b = (const float*)d_in[8];
  const float* ur1  = (const float*)d_in[9];
  const float* wr1w = (const float*)d_in[10];
  const float* wr1b = (const float*)d_in[11];
  const float* uh1  = (const float*)d_in[12];
  const float* wh1w = (const float*)d_in[13];
  const float* wh1b = (const float*)d_in[14];
  const float* w4   = (const float*)d_in[27];
  float* y = (float*)d_out;

  uint8_t* ws = (uint8_t*)d_ws;
  size_t off = 0;
  auto carve = [&](size_t bytes) -> void* {
    void* p = ws + off;
    off += (bytes + 255) & ~(size_t)255;
    return p;
  };
  u16* xa  = (u16*)carve((size_t)BATCH * NIN * 2);    //  8 MB
  u16* r1  = (u16*)carve((size_t)BATCH * NHID * 2);   // 32 MB
  u16* s1  = (u16*)carve((size_t)BATCH * NHID * 2);   // 32 MB
  u16* bug = (u16*)carve((size_t)NHID * NIN * 2);
  u16* buz = (u16*)carve((size_t)NHID * NIN * 2);
  u16* bur = (u16*)carve((size_t)NHID * NIN * 2);
  u16* buh = (u16*)carve((size_t)NHID * NIN * 2);
  u16* bwh = (u16*)carve((size_t)NHID * NHID * 2);
  u16* bw4 = (u16*)carve((size_t)NOUT * NHID * 2);
  float* cg = (float*)carve(NHID * 4);
  float* cz = (float*)carve(NHID * 4);
  float* cr = (float*)carve(NHID * 4);

  Prep P;
  P.x = x; P.xa = xa;
  P.csrc[0] = ug1;  P.cdst[0] = bug; P.cblk[0] = 256;
  P.csrc[1] = uz1;  P.cdst[1] = buz; P.cblk[1] = 256;
  P.csrc[2] = ur1;  P.cdst[2] = bur; P.cblk[2] = 256;
  P.csrc[3] = uh1;  P.cdst[3] = buh; P.cblk[3] = 256;
  P.csrc[4] = wh1w; P.cdst[4] = bwh; P.cblk[4] = 1024;
  P.csrc[5] = w4;   P.cdst[5] = bw4; P.cblk[5] = 256;
  P.w[0] = wg1w; P.bb[0] = wg1b; P.c[0] = cg;
  P.w[1] = wz1w; P.bb[1] = wz1b; P.c[1] = cz;
  P.w[2] = wr1w; P.bb[2] = wr1b; P.c[2] = cr;
  k_prep<<<9472, 256, 0, stream>>>(P);

  k_pass_r<<<dim3(NHID / BN, BATCH / BM), 256, 0, stream>>>(xa, bur, cr, r1);

  k_gates_h512<<<(BATCH / 256) * (NHID / 128), 512, 147456, stream>>>(
      xa, bug, buz, buh, cg, cz, wh1b, r1, bwh, s1);

  k_pass_c<<<dim3(NOUT / BN, BATCH / BM), 256, 0, stream>>>(s1, bw4, y);
}

// Round 22
// 135.511 us; speedup vs baseline: 1.0155x; 1.0155x over previous
//
#include <hip/hip_runtime.h>
#include <hip/hip_bf16.h>
#include <stdint.h>

// ---------------------------------------------------------------------------
// y = w4( s1 ),  s1 = (1-g1)*h1 + z1   (s0 == 1 exactly: tanh saturation)
// R20/R21: gates_h512 = 96-97us, staging-BW-capped (~7.2TB/s L2->LDS; 2-deep
//   prefetch null). Total 137us vs ~125-135 structural floor (956MB staged).
// R22: (a) port pass_r to the verified 256x128/512thr frame (134->98MB
//   staged); (b) revert gates to 2-buffer 96KB LDS (R21 3-buf was null).
// Tile growth beyond 256x128 is blocked by MEASURED compiler caps:
//   128 VGPR @512thr, spill >~205 @256thr.
// ---------------------------------------------------------------------------

typedef unsigned short u16;
using f32x4  = __attribute__((ext_vector_type(4))) float;
using bf16x8 = __attribute__((ext_vector_type(8))) short;

#define BATCH 16384
#define NIN   256
#define NHID  1024
#define NOUT  256

#define BM 128
#define BN 128
#define BK2 64   // K-chunk per pipeline step (128B rows in LDS)

__device__ __forceinline__ u16 f2bf(float f) {
  unsigned u = __builtin_bit_cast(unsigned, f);
  unsigned r = 0x7fffu + ((u >> 16) & 1u);
  return (u16)((u + r) >> 16);
}
__device__ __forceinline__ float bf2f(u16 h) {
  unsigned u = ((unsigned)h) << 16;
  return __builtin_bit_cast(float, u);
}
__device__ __forceinline__ float fast_tanh(float x) {
  float cx = fminf(fmaxf(x, -15.f), 15.f);
  float e  = __expf(2.f * cx);
  return (e - 1.f) / (e + 1.f);
}

__device__ __forceinline__ void gload_lds16(const u16* g, u16* l) {
  __builtin_amdgcn_global_load_lds(
      (__attribute__((address_space(1))) void*)(const_cast<u16*>(g)),
      (__attribute__((address_space(3))) void*)(l),
      16, 0, 0);
}

// ================= 128^2 / 4-wave machinery (R8/R14, verified) ==============

__device__ __forceinline__ void stage64(const u16* g0, int ld, u16* lds) {
  int t = threadIdx.x;
#pragma unroll
  for (int iss = 0; iss < 4; ++iss) {
    int idx = t + iss * 256;
    int row = idx >> 3;
    int j   = idx & 7;
    int c   = (j ^ (row & 7)) << 3;
    gload_lds16(g0 + (size_t)row * ld + c, lds + (size_t)idx * 8);
  }
}

__device__ __forceinline__ void mfma64(const u16* As, const u16* Bs,
                                       int wm, int wn, int lane,
                                       f32x4 acc[4][4]) {
  int r  = lane & 15;
  int q  = lane >> 4;
  int xr = r & 7;
#pragma unroll
  for (int ks = 0; ks < 2; ++ks) {
    int cx = ((ks * 4 + q) ^ xr) << 3;
    bf16x8 a[4], b[4];
#pragma unroll
    for (int i = 0; i < 4; ++i)
      a[i] = *(const bf16x8*)(As + (size_t)((wm + i * 16 + r) * BK2 + cx));
#pragma unroll
    for (int j = 0; j < 4; ++j)
      b[j] = *(const bf16x8*)(Bs + (size_t)((wn + j * 16 + r) * BK2 + cx));
#pragma unroll
    for (int i = 0; i < 4; ++i)
#pragma unroll
      for (int j = 0; j < 4; ++j)
        acc[i][j] = __builtin_amdgcn_mfma_f32_16x16x32_bf16(a[i], b[j], acc[i][j], 0, 0, 0);
  }
}

__device__ __forceinline__ void pipe_step(const u16* At, int lda,
                                          const u16* Bt, int ldb,
                                          int t, int STEPS,
                                          u16* Ac, u16* Bc, u16* An, u16* Bn,
                                          int wm, int wn, int lane,
                                          f32x4 acc[4][4]) {
  if (t + 1 < STEPS) {
    stage64(At + (size_t)(t + 1) * BK2, lda, An);
    stage64(Bt + (size_t)(t + 1) * BK2, ldb, Bn);
    asm volatile("s_waitcnt vmcnt(8)" ::: "memory");
  } else {
    asm volatile("s_waitcnt vmcnt(0)" ::: "memory");
  }
  __builtin_amdgcn_s_barrier();
  mfma64(Ac, Bc, wm, wn, lane, acc);
  asm volatile("s_waitcnt lgkmcnt(0)" ::: "memory");
  __builtin_amdgcn_s_barrier();
}

template<int STEPS>
__device__ __forceinline__ void gemm_pipe(const u16* A, int lda,
                                          const u16* B, int ldb,
                                          int m0, int n0, u16* sm,
                                          int wm, int wn, int lane,
                                          f32x4 acc[4][4]) {
  const u16* At = A + (size_t)m0 * lda;
  const u16* Bt = B + (size_t)n0 * ldb;
  u16* As0 = sm;          u16* Bs0 = sm + 8192;
  u16* As1 = sm + 16384;  u16* Bs1 = sm + 24576;
  stage64(At, lda, As0);
  stage64(Bt, ldb, Bs0);
  static_assert(STEPS % 2 == 0, "even steps");
#pragma unroll
  for (int tt = 0; tt < STEPS / 2; ++tt) {
    pipe_step(At, lda, Bt, ldb, 2 * tt,     STEPS, As0, Bs0, As1, Bs1, wm, wn, lane, acc);
    pipe_step(At, lda, Bt, ldb, 2 * tt + 1, STEPS, As1, Bs1, As0, Bs0, wm, wn, lane, acc);
  }
}

__device__ __forceinline__ void zero_acc(f32x4 acc[4][4]) {
  f32x4 z = {0.f, 0.f, 0.f, 0.f};
#pragma unroll
  for (int i = 0; i < 4; ++i)
#pragma unroll
    for (int j = 0; j < 4; ++j) acc[i][j] = z;
}

// ================= 256x128 / 8-wave machinery (R17/R18, verified) ===========
// Per buffer: A 256x64 (16384 u16) + B 128x64 (8192 u16) = 48KB; dbuf 96KB.

__device__ __forceinline__ void stageA8(const u16* g0, int ld, u16* lds) {
  int t = threadIdx.x;
#pragma unroll
  for (int iss = 0; iss < 4; ++iss) {
    int idx = t + iss * 512;        // 0..2047
    int row = idx >> 3;             // 0..255
    int j   = idx & 7;
    int c   = (j ^ (row & 7)) << 3;
    gload_lds16(g0 + (size_t)row * ld + c, lds + (size_t)idx * 8);
  }
}
__device__ __forceinline__ void stageB8(const u16* g0, int ld, u16* lds) {
  int t = threadIdx.x;
#pragma unroll
  for (int iss = 0; iss < 2; ++iss) {
    int idx = t + iss * 512;        // 0..1023
    int row = idx >> 3;             // 0..127
    int j   = idx & 7;
    int c   = (j ^ (row & 7)) << 3;
    gload_lds16(g0 + (size_t)row * ld + c, lds + (size_t)idx * 8);
  }
}

__device__ __forceinline__ void pipe_step8(const u16* At, int lda,
                                           const u16* Bt, int ldb,
                                           int t, int STEPS, u16* sm,
                                           int wm, int wn, int lane,
                                           f32x4 acc[4][4]) {
  if (t + 1 < STEPS) {
    u16* nb = sm + (size_t)((t + 1) & 1) * 24576;
    stageA8(At + (size_t)(t + 1) * BK2, lda, nb);
    stageB8(Bt + (size_t)(t + 1) * BK2, ldb, nb + 16384);
    asm volatile("s_waitcnt vmcnt(6)" ::: "memory");
  } else {
    asm volatile("s_waitcnt vmcnt(0)" ::: "memory");
  }
  __builtin_amdgcn_s_barrier();
  u16* cur = sm + (size_t)(t & 1) * 24576;
  mfma64(cur, cur + 16384, wm, wn, lane, acc);
  asm volatile("s_waitcnt lgkmcnt(0)" ::: "memory");
  __builtin_amdgcn_s_barrier();
}

template<int STEPS>
__device__ __forceinline__ void gemm_pipe8(const u16* A, int lda,
                                           const u16* B, int ldb,
                                           int m0, int n0, u16* sm,
                                           int wm, int wn, int lane,
                                           f32x4 acc[4][4]) {
  const u16* At = A + (size_t)m0 * lda;
  const u16* Bt = B + (size_t)n0 * ldb;
  stageA8(At, lda, sm);
  stageB8(Bt, ldb, sm + 16384);
#pragma unroll
  for (int t = 0; t < STEPS; ++t)
    pipe_step8(At, lda, Bt, ldb, t, STEPS, sm, wm, wn, lane, acc);
}

// --------------------------- fused prep kernel ------------------------------

struct Prep {
  const float* x; u16* xa;
  const float* csrc[6]; u16* cdst[6]; int cblk[6];
  const float* w[3]; const float* bb[3]; float* c[3];
};

__global__ __launch_bounds__(256) void k_prep(Prep P) {
  int b = blockIdx.x;
  if (b < 4096) {
    int i = b * 256 + threadIdx.x;
    float4 v = ((const float4*)P.x)[i];
    ushort4 o;
    o.x = f2bf(fabsf(v.x) + 0.1f);
    o.y = f2bf(fabsf(v.y) + 0.1f);
    o.z = f2bf(fabsf(v.z) + 0.1f);
    o.w = f2bf(fabsf(v.w) + 0.1f);
    ((ushort4*)P.xa)[i] = o;
  } else if (b < 6400) {
    int rb = b - 4096;
    int k = 0;
#pragma unroll
    for (int t = 0; t < 5; ++t)
      if (rb >= P.cblk[k]) { rb -= P.cblk[k]; ++k; }
    int i = rb * 256 + threadIdx.x;
    float4 v = ((const float4*)P.csrc[k])[i];
    ushort4 o;
    o.x = f2bf(v.x); o.y = f2bf(v.y); o.z = f2bf(v.z); o.w = f2bf(v.w);
    ((ushort4*)P.cdst[k])[i] = o;
  } else {
    int rb = b - 6400;
    int g = rb >> 10, n = rb & 1023;
    const float* row = P.w[g] + (size_t)n * NHID;
    float s = 0.f;
    for (int k = threadIdx.x; k < NHID; k += 256) s += row[k];
#pragma unroll
    for (int o = 32; o; o >>= 1) s += __shfl_down(s, o, 64);
    __shared__ float sm[4];
    if ((threadIdx.x & 63) == 0) sm[threadIdx.x >> 6] = s;
    __syncthreads();
    if (threadIdx.x == 0) P.c[g][n] = sm[0] + sm[1] + sm[2] + sm[3] + P.bb[g][n];
  }
}

// --------------------------- GEMM passes -----------------------------------

// r1 = tanh(xa @ ur.T + cr)  -- 256x128 / 512thr frame (R22 port)
__global__ __launch_bounds__(512, 1) void k_pass_r512(
    const u16* __restrict__ xa, const u16* __restrict__ ur,
    const float* __restrict__ cr, u16* __restrict__ r1) {
  extern __shared__ __align__(16) u16 smem[];   // 96KB dynamic

  int bid = blockIdx.x;                 // 512 = 8 xcd x 8 m x 8 n
  int xcd = bid & 7;
  int idx = bid >> 3;
  int mb  = xcd * 8 + (idx >> 3);
  int nb  = idx & 7;
  int m0 = mb * 256, n0 = nb * 128;

  int lane = threadIdx.x & 63, wave = threadIdx.x >> 6;
  int wm = (wave >> 1) * 64;
  int wn = (wave & 1) * 64;
  int crw = (lane >> 4) * 4, cc = lane & 15;

  f32x4 acc[4][4];
  zero_acc(acc);
  gemm_pipe8<4>(xa, NIN, ur, NIN, m0, n0, smem, wm, wn, lane, acc);

#pragma unroll
  for (int ni = 0; ni < 4; ++ni) {
    int col = n0 + wn + ni * 16 + cc;
    float bias = cr[col];
#pragma unroll
    for (int mi = 0; mi < 4; ++mi)
#pragma unroll
      for (int r = 0; r < 4; ++r) {
        int row = m0 + wm + mi * 16 + crw + r;
        r1[(size_t)row * NHID + col] = f2bf(fast_tanh(acc[mi][ni][r] + bias));
      }
  }
}

// Fused gates+h at 256x128, 8 waves, h->g->z order (R18), 2-buffer pipe.
__global__ __launch_bounds__(512, 1) void k_gates_h512(
    const u16* __restrict__ xa,
    const u16* __restrict__ ug, const u16* __restrict__ uz,
    const u16* __restrict__ uh,
    const float* __restrict__ cg, const float* __restrict__ cz,
    const float* __restrict__ bh,
    const u16* __restrict__ r1, const u16* __restrict__ wh,
    u16* __restrict__ s1) {
  extern __shared__ __align__(16) u16 smem[];   // 96KB dynamic

  int bid = blockIdx.x;
  int xcd = bid & 7;
  int idx = bid >> 3;
  int mb  = xcd * 8 + (idx >> 3);
  int nb  = idx & 7;
  int m0 = mb * 256, n0 = nb * 128;

  int lane = threadIdx.x & 63, wave = threadIdx.x >> 6;
  int wm = (wave >> 1) * 64;
  int wn = (wave & 1) * 64;
  int crw = (lane >> 4) * 4, cc = lane & 15;

  f32x4 acc[4][4];
  unsigned ph[4][4][2];   // packed h, then packed sp = (1-g)*h

  // ---- h (long phase, 20 steps, minimal live state) ----
  zero_acc(acc);
  gemm_pipe8<4>(xa, NIN, uh, NIN, m0, n0, smem, wm, wn, lane, acc);
  gemm_pipe8<16>(r1, NHID, wh, NHID, m0, n0, smem, wm, wn, lane, acc);
#pragma unroll
  for (int ni = 0; ni < 4; ++ni) {
    float bias = bh[n0 + wn + ni * 16 + cc];
#pragma unroll
    for (int mi = 0; mi < 4; ++mi) {
      float h0 = fast_tanh(acc[mi][ni][0] + bias);
      float h1 = fast_tanh(acc[mi][ni][1] + bias);
      float h2 = fast_tanh(acc[mi][ni][2] + bias);
      float h3 = fast_tanh(acc[mi][ni][3] + bias);
      ph[mi][ni][0] = (unsigned)f2bf(h0) | ((unsigned)f2bf(h1) << 16);
      ph[mi][ni][1] = (unsigned)f2bf(h2) | ((unsigned)f2bf(h3) << 16);
    }
  }

  // ---- gate g: sp = (1 - tanh(g+cg)) * h ----
  zero_acc(acc);
  gemm_pipe8<4>(xa, NIN, ug, NIN, m0, n0, smem, wm, wn, lane, acc);
#pragma unroll
  for (int ni = 0; ni < 4; ++ni) {
    float cv = cg[n0 + wn + ni * 16 + cc];
#pragma unroll
    for (int mi = 0; mi < 4; ++mi) {
      float g0 = 1.f - fast_tanh(acc[mi][ni][0] + cv);
      float g1 = 1.f - fast_tanh(acc[mi][ni][1] + cv);
      float g2 = 1.f - fast_tanh(acc[mi][ni][2] + cv);
      float g3 = 1.f - fast_tanh(acc[mi][ni][3] + cv);
      unsigned w0 = ph[mi][ni][0], w1 = ph[mi][ni][1];
      float s0 = g0 * bf2f((u16)(w0 & 0xffff));
      float s1v = g1 * bf2f((u16)(w0 >> 16));
      float s2 = g2 * bf2f((u16)(w1 & 0xffff));
      float s3 = g3 * bf2f((u16)(w1 >> 16));
      ph[mi][ni][0] = (unsigned)f2bf(s0) | ((unsigned)f2bf(s1v) << 16);
      ph[mi][ni][1] = (unsigned)f2bf(s2) | ((unsigned)f2bf(s3) << 16);
    }
  }

  // ---- gate z: s1 = sp + tanh(z+cz), write ----
  zero_acc(acc);
  gemm_pipe8<4>(xa, NIN, uz, NIN, m0, n0, smem, wm, wn, lane, acc);
#pragma unroll
  for (int ni = 0; ni < 4; ++ni) {
    int col = n0 + wn + ni * 16 + cc;
    float cv = cz[col];
#pragma unroll
    for (int mi = 0; mi < 4; ++mi)
#pragma unroll
      for (int r = 0; r < 4; ++r) {
        int row = m0 + wm + mi * 16 + crw + r;
        float z = fast_tanh(acc[mi][ni][r] + cv);
        unsigned w = ph[mi][ni][r >> 1];
        float sp = bf2f((r & 1) ? (u16)(w >> 16) : (u16)(w & 0xffff));
        s1[(size_t)row * NHID + col] = f2bf(sp + z);
      }
  }
}

// y = s1 @ w4.T (fp32 out)   (R14, verified)
__global__ __launch_bounds__(256) void k_pass_c(const u16* __restrict__ s1,
                                                const u16* __restrict__ w4,
                                                float* __restrict__ y) {
  __shared__ __align__(16) u16 smem[32768];
  int m0 = blockIdx.y * BM, n0 = blockIdx.x * BN;
  int lane = threadIdx.x & 63, wave = threadIdx.x >> 6;
  int wm = (wave >> 1) * 64, wn = (wave & 1) * 64;
  f32x4 acc[4][4];
  zero_acc(acc);
  gemm_pipe<16>(s1, NHID, w4, NHID, m0, n0, smem, wm, wn, lane, acc);

  int crw = (lane >> 4) * 4, cc = lane & 15;
#pragma unroll
  for (int ni = 0; ni < 4; ++ni) {
    int col = n0 + wn + ni * 16 + cc;
#pragma unroll
    for (int mi = 0; mi < 4; ++mi)
#pragma unroll
      for (int r = 0; r < 4; ++r) {
        int row = m0 + wm + mi * 16 + crw + r;
        y[(size_t)row * NOUT + col] = acc[mi][ni][r];
      }
  }
}

// --------------------------- host ------------------------------------------

extern "C" void kernel_launch(void* const* d_in, const int* in_sizes, int n_in,
                              void* d_out, int out_size, void* d_ws, size_t ws_size,
                              hipStream_t stream) {
  (void)in_sizes; (void)n_in; (void)out_size; (void)ws_size;

  const float* x    = (const float*)d_in[0];
  const float* ug1  = (const float*)d_in[3];
  const float* wg1w = (const float*)d_in[4];
  const float* wg1b = (const float*)d_in[5];
  const float* uz1  = (const float*)d_in[6];
  const float* wz1w = (const float*)d_in[7];
  const float* wz1b = (const float*)d_in[8];
  const float* ur1  = (const float*)d_in[9];
  const float* wr1w = (const float*)d_in[10];
  const float* wr1b = (const float*)d_in[11];
  const float* uh1  = (const float*)d_in[12];
  const float* wh1w = (const float*)d_in[13];
  const float* wh1b = (const float*)d_in[14];
  const float* w4   = (const float*)d_in[27];
  float* y = (float*)d_out;

  uint8_t* ws = (uint8_t*)d_ws;
  size_t off = 0;
  auto carve = [&](size_t bytes) -> void* {
    void* p = ws + off;
    off += (bytes + 255) & ~(size_t)255;
    return p;
  };
  u16* xa  = (u16*)carve((size_t)BATCH * NIN * 2);    //  8 MB
  u16* r1  = (u16*)carve((size_t)BATCH * NHID * 2);   // 32 MB
  u16* s1  = (u16*)carve((size_t)BATCH * NHID * 2);   // 32 MB
  u16* bug = (u16*)carve((size_t)NHID * NIN * 2);
  u16* buz = (u16*)carve((size_t)NHID * NIN * 2);
  u16* bur = (u16*)carve((size_t)NHID * NIN * 2);
  u16* buh = (u16*)carve((size_t)NHID * NIN * 2);
  u16* bwh = (u16*)carve((size_t)NHID * NHID * 2);
  u16* bw4 = (u16*)carve((size_t)NOUT * NHID * 2);
  float* cg = (float*)carve(NHID * 4);
  float* cz = (float*)carve(NHID * 4);
  float* cr = (float*)carve(NHID * 4);

  Prep P;
  P.x = x; P.xa = xa;
  P.csrc[0] = ug1;  P.cdst[0] = bug; P.cblk[0] = 256;
  P.csrc[1] = uz1;  P.cdst[1] = buz; P.cblk[1] = 256;
  P.csrc[2] = ur1;  P.cdst[2] = bur; P.cblk[2] = 256;
  P.csrc[3] = uh1;  P.cdst[3] = buh; P.cblk[3] = 256;
  P.csrc[4] = wh1w; P.cdst[4] = bwh; P.cblk[4] = 1024;
  P.csrc[5] = w4;   P.cdst[5] = bw4; P.cblk[5] = 256;
  P.w[0] = wg1w; P.bb[0] = wg1b; P.c[0] = cg;
  P.w[1] = wz1w; P.bb[1] = wz1b; P.c[1] = cz;
  P.w[2] = wr1w; P.bb[2] = wr1b; P.c[2] = cr;
  k_prep<<<9472, 256, 0, stream>>>(P);

  k_pass_r512<<<(BATCH / 256) * (NHID / 128), 512, 98304, stream>>>(
      xa, bur, cr, r1);

  k_gates_h512<<<(BATCH / 256) * (NHID / 128), 512, 98304, stream>>>(
      xa, bug, buz, buh, cg, cz, wh1b, r1, bwh, s1);

  k_pass_c<<<dim3(NOUT / BN, BATCH / BM), 256, 0, stream>>>(s1, bw4, y);
}